// Round 6
// baseline (579.212 us; speedup 1.0000x reference)
//
#include <hip/hip_runtime.h>

#define NBINS 15

typedef float f32x4 __attribute__((ext_vector_type(4)));

// 4 lanes per row, 16 rows per wave-iteration, software-pipelined prefetch.
// Lane layout: sub = lane&3 (float4 slot), rIw = lane>>2 (row within wave).
// LDS histogram replicated 16x (indexed by rIw) so the 16 active lanes of a
// wave never hit the same address -> no LDS atomic serialization.
// d_ws layout: [0..14]=count, [15..29]=conf_sum, [30..44]=acc_sum, [48]=ticket
// NOTE: plain __launch_bounds__(256) — (256,8) squeezed VGPR to 32 and
// serialized the in-flight loads (R3: 593us vs R2: 190us).
__global__ __launch_bounds__(256) void ece_fused(
    const f32x4* __restrict__ logits4,
    const int*   __restrict__ labels,
    const float* __restrict__ temperature,
    float*       __restrict__ gbins,
    int*         __restrict__ ticket,
    float*       __restrict__ out,
    int N, int nblocks)
{
    __shared__ float sbins[16][3 * NBINS];   // 16 replicas, stride 45 (odd)
    const int tid = threadIdx.x;
    for (int i = tid; i < 16 * 3 * NBINS; i += 256)
        (&sbins[0][0])[i] = 0.0f;
    __syncthreads();

    const float invT = 1.0f / temperature[0];

    const int lane = tid & 63;
    const int wIn  = tid >> 6;
    const long long gWave = (long long)blockIdx.x * 4 + wIn;
    const long long nWave = (long long)gridDim.x * 4;
    const long long step  = nWave * 16;

    const int sub = lane & 3;   // float4 slot group
    const int rIw = lane >> 2;  // row within wave (0..15) == LDS replica

    long long r0 = gWave * 16;
    if (r0 < (long long)N) {
        long long row   = r0 + rIw;
        bool     cvalid = row < (long long)N;
        long long crc   = cvalid ? row : (long long)(N - 1);

        // prologue: load current batch
        const f32x4* p = logits4 + crc * 16 + sub;
        f32x4 c0 = __builtin_nontemporal_load(p);
        f32x4 c1 = __builtin_nontemporal_load(p + 4);
        f32x4 c2 = __builtin_nontemporal_load(p + 8);
        f32x4 c3 = __builtin_nontemporal_load(p + 12);
        int   clbl = labels[crc];

        for (;;) {
            const long long nr0 = r0 + step;
            const bool have_next = nr0 < (long long)N;   // wave-uniform

            f32x4 n0, n1, n2, n3; int nlbl = 0; bool nvalid = false;
            if (have_next) {
                const long long nrow = nr0 + rIw;
                nvalid = nrow < (long long)N;
                const long long nrc = nvalid ? nrow : (long long)(N - 1);
                const f32x4* np = logits4 + nrc * 16 + sub;
                n0 = __builtin_nontemporal_load(np);
                n1 = __builtin_nontemporal_load(np + 4);
                n2 = __builtin_nontemporal_load(np + 8);
                n3 = __builtin_nontemporal_load(np + 12);
                nlbl = labels[nrc];
            }

            // ---- process current batch ----
            // exps are independent of the max (no max-subtraction; |x|/T < ~6)
            float s;
            {
                const float a0 = __expf(c0.x * invT), a1 = __expf(c0.y * invT);
                const float a2 = __expf(c0.z * invT), a3 = __expf(c0.w * invT);
                const float b0 = __expf(c1.x * invT), b1 = __expf(c1.y * invT);
                const float b2 = __expf(c1.z * invT), b3 = __expf(c1.w * invT);
                const float e0 = __expf(c2.x * invT), e1 = __expf(c2.y * invT);
                const float e2 = __expf(c2.z * invT), e3 = __expf(c2.w * invT);
                const float d0 = __expf(c3.x * invT), d1 = __expf(c3.y * invT);
                const float d2 = __expf(c3.z * invT), d3 = __expf(c3.w * invT);
                s = (((a0 + a1) + (a2 + a3)) + ((b0 + b1) + (b2 + b3)))
                  + (((e0 + e1) + (e2 + e3)) + ((d0 + d1) + (d2 + d3)));
            }

            float m = fmaxf(fmaxf(fmaxf(c0.x, c0.y), fmaxf(c0.z, c0.w)),
                            fmaxf(fmaxf(c1.x, c1.y), fmaxf(c1.z, c1.w)));
            m = fmaxf(m, fmaxf(fmaxf(fmaxf(c2.x, c2.y), fmaxf(c2.z, c2.w)),
                               fmaxf(fmaxf(c3.x, c3.y), fmaxf(c3.z, c3.w))));

            s += __shfl_xor(s, 1);
            s += __shfl_xor(s, 2);
            m = fmaxf(m, __shfl_xor(m, 1));
            m = fmaxf(m, __shfl_xor(m, 2));

            const float conf = __expf(m * invT) * __builtin_amdgcn_rcpf(s);
            int bin = (int)ceilf(conf * (float)NBINS) - 1;
            bin = bin < 0 ? 0 : (bin > NBINS - 1 ? NBINS - 1 : bin);

            if (cvalid) {
                if (sub == 0) {
                    atomicAdd(&sbins[rIw][bin],         1.0f);
                    atomicAdd(&sbins[rIw][NBINS + bin], conf);
                }
                // accuracy: is the label's logit the row max?
                // owning lane: col = 4*sub + 16*k + j -> sub = (lbl>>2)&3
                if (((clbl >> 2) & 3) == sub) {
                    const int k = clbl >> 4;
                    const int j = clbl & 3;
                    const f32x4 vk = (k < 2) ? ((k & 1) ? c1 : c0)
                                             : ((k & 1) ? c3 : c2);
                    const float vl = (j < 2) ? ((j & 1) ? vk.y : vk.x)
                                             : ((j & 1) ? vk.w : vk.z);
                    if (vl == m) atomicAdd(&sbins[rIw][2 * NBINS + bin], 1.0f);
                }
            }
            // ---- end process ----

            if (!have_next) break;
            c0 = n0; c1 = n1; c2 = n2; c3 = n3;
            clbl = nlbl; cvalid = nvalid;
            r0 = nr0;
        }
    }

    __syncthreads();
    if (tid < 3 * NBINS) {
        float v = 0.0f;
        #pragma unroll
        for (int r = 0; r < 16; ++r) v += sbins[r][tid];
        if (v != 0.0f) atomicAdd(&gbins[tid], v);
    }

    // last block finalizes (ticket scheme verified in R3)
    __threadfence();
    if (tid == 0) {
        const int t = atomicAdd(ticket, 1);
        if (t == nblocks - 1) {
            const float invN = 1.0f / (float)N;
            float ece = 0.0f, mce = 0.0f;
            #pragma unroll
            for (int i = 0; i < NBINS; ++i) {
                // read through L2 (atomic) to avoid stale L1 lines
                const float c  = atomicAdd(&gbins[i],             0.0f);
                const float cs = atomicAdd(&gbins[NBINS + i],     0.0f);
                const float as = atomicAdd(&gbins[2 * NBINS + i], 0.0f);
                if (c > 0.0f) {
                    const float gap = fabsf(cs / c - as / c);
                    ece += gap * (c * invN);
                    mce = fmaxf(mce, gap);
                }
            }
            out[0] = ece;
            out[1] = mce;
        }
    }
}

extern "C" void kernel_launch(void* const* d_in, const int* in_sizes, int n_in,
                              void* d_out, int out_size, void* d_ws, size_t ws_size,
                              hipStream_t stream) {
    const f32x4* logits4     = (const f32x4*)d_in[0];
    const int*   labels      = (const int*)d_in[1];
    const float* temperature = (const float*)d_in[2];
    float*       out         = (float*)d_out;
    float*       gbins       = (float*)d_ws;
    int*         ticket      = (int*)d_ws + 48;

    const int N = in_sizes[1];  // number of rows / labels

    hipMemsetAsync(d_ws, 0, 64 * sizeof(float), stream);

    const int block = 256;
    const int grid  = 2048;
    ece_fused<<<grid, block, 0, stream>>>(logits4, labels, temperature,
                                          gbins, ticket, out, N, grid);
}

// Round 7
// 184.831 us; speedup vs baseline: 3.1337x; 3.1337x over previous
//
#include <hip/hip_runtime.h>

#define NBINS 15

typedef float f32x4 __attribute__((ext_vector_type(4)));

// 4 lanes per row, 16 rows per wave-iteration, software-pipelined prefetch.
// Lane layout: sub = lane&3 (float4 slot), rIw = lane>>2 (row within wave).
// LDS histogram replicated 16x (indexed by rIw): the 16 active lanes of a
// wave hit distinct replicas -> no same-address LDS atomic serialization.
// Replica stride 45 floats (odd) -> banks rIw*13 mod 32, all distinct.
// d_ws layout: [0..14]=count, [15..29]=conf_sum, [30..44]=acc_sum
// NOTE: separate finalize kernel — the fused ticket/__threadfence version
// compiled to 32 VGPR and ran 3x slower (R3: 593us, R6: 579us).
// NOTE: plain __launch_bounds__(256); no min-waves clause.
__global__ __launch_bounds__(256) void ece_partial(
    const f32x4* __restrict__ logits4,
    const int*   __restrict__ labels,
    const float* __restrict__ temperature,
    float*       __restrict__ gbins,
    int N)
{
    __shared__ float sbins[16][3 * NBINS];   // 16 replicas
    const int tid = threadIdx.x;
    for (int i = tid; i < 16 * 3 * NBINS; i += 256)
        (&sbins[0][0])[i] = 0.0f;
    __syncthreads();

    const float invT = 1.0f / temperature[0];

    const int lane = tid & 63;
    const int wIn  = tid >> 6;
    const long long gWave = (long long)blockIdx.x * 4 + wIn;
    const long long nWave = (long long)gridDim.x * 4;
    const long long step  = nWave * 16;

    const int sub = lane & 3;   // float4 slot group
    const int rIw = lane >> 2;  // row within wave (0..15) == LDS replica

    long long r0 = gWave * 16;
    if (r0 < (long long)N) {
        long long row   = r0 + rIw;
        bool     cvalid = row < (long long)N;
        long long crc   = cvalid ? row : (long long)(N - 1);

        // prologue: load current batch
        const f32x4* p = logits4 + crc * 16 + sub;
        f32x4 c0 = __builtin_nontemporal_load(p);
        f32x4 c1 = __builtin_nontemporal_load(p + 4);
        f32x4 c2 = __builtin_nontemporal_load(p + 8);
        f32x4 c3 = __builtin_nontemporal_load(p + 12);
        int   clbl = labels[crc];

        for (;;) {
            const long long nr0 = r0 + step;
            const bool have_next = nr0 < (long long)N;   // wave-uniform

            f32x4 n0, n1, n2, n3; int nlbl = 0; bool nvalid = false;
            if (have_next) {
                const long long nrow = nr0 + rIw;
                nvalid = nrow < (long long)N;
                const long long nrc = nvalid ? nrow : (long long)(N - 1);
                const f32x4* np = logits4 + nrc * 16 + sub;
                n0 = __builtin_nontemporal_load(np);
                n1 = __builtin_nontemporal_load(np + 4);
                n2 = __builtin_nontemporal_load(np + 8);
                n3 = __builtin_nontemporal_load(np + 12);
                nlbl = labels[nrc];
            }

            // ---- process current batch ----
            // exps are independent of the max (no max-subtraction; |x|/T < ~6)
            float s;
            {
                const float a0 = __expf(c0.x * invT), a1 = __expf(c0.y * invT);
                const float a2 = __expf(c0.z * invT), a3 = __expf(c0.w * invT);
                const float b0 = __expf(c1.x * invT), b1 = __expf(c1.y * invT);
                const float b2 = __expf(c1.z * invT), b3 = __expf(c1.w * invT);
                const float e0 = __expf(c2.x * invT), e1 = __expf(c2.y * invT);
                const float e2 = __expf(c2.z * invT), e3 = __expf(c2.w * invT);
                const float d0 = __expf(c3.x * invT), d1 = __expf(c3.y * invT);
                const float d2 = __expf(c3.z * invT), d3 = __expf(c3.w * invT);
                s = (((a0 + a1) + (a2 + a3)) + ((b0 + b1) + (b2 + b3)))
                  + (((e0 + e1) + (e2 + e3)) + ((d0 + d1) + (d2 + d3)));
            }

            float m = fmaxf(fmaxf(fmaxf(c0.x, c0.y), fmaxf(c0.z, c0.w)),
                            fmaxf(fmaxf(c1.x, c1.y), fmaxf(c1.z, c1.w)));
            m = fmaxf(m, fmaxf(fmaxf(fmaxf(c2.x, c2.y), fmaxf(c2.z, c2.w)),
                               fmaxf(fmaxf(c3.x, c3.y), fmaxf(c3.z, c3.w))));

            s += __shfl_xor(s, 1);
            s += __shfl_xor(s, 2);
            m = fmaxf(m, __shfl_xor(m, 1));
            m = fmaxf(m, __shfl_xor(m, 2));

            const float conf = __expf(m * invT) * __builtin_amdgcn_rcpf(s);
            int bin = (int)ceilf(conf * (float)NBINS) - 1;
            bin = bin < 0 ? 0 : (bin > NBINS - 1 ? NBINS - 1 : bin);

            if (cvalid) {
                if (sub == 0) {
                    atomicAdd(&sbins[rIw][bin],         1.0f);
                    atomicAdd(&sbins[rIw][NBINS + bin], conf);
                }
                // accuracy: is the label's logit the row max?
                // owning lane: col = 4*sub + 16*k + j -> sub = (lbl>>2)&3
                if (((clbl >> 2) & 3) == sub) {
                    const int k = clbl >> 4;
                    const int j = clbl & 3;
                    const f32x4 vk = (k < 2) ? ((k & 1) ? c1 : c0)
                                             : ((k & 1) ? c3 : c2);
                    const float vl = (j < 2) ? ((j & 1) ? vk.y : vk.x)
                                             : ((j & 1) ? vk.w : vk.z);
                    if (vl == m) atomicAdd(&sbins[rIw][2 * NBINS + bin], 1.0f);
                }
            }
            // ---- end process ----

            if (!have_next) break;
            c0 = n0; c1 = n1; c2 = n2; c3 = n3;
            clbl = nlbl; cvalid = nvalid;
            r0 = nr0;
        }
    }

    __syncthreads();
    if (tid < 3 * NBINS) {
        float v = 0.0f;
        #pragma unroll
        for (int r = 0; r < 16; ++r) v += sbins[r][tid];
        if (v != 0.0f) atomicAdd(&gbins[tid], v);
    }
}

__global__ void ece_finalize(const float* __restrict__ gbins,
                             float* __restrict__ out, float invN)
{
    if (threadIdx.x == 0 && blockIdx.x == 0) {
        float ece = 0.0f, mce = 0.0f;
        #pragma unroll
        for (int i = 0; i < NBINS; ++i) {
            const float c  = gbins[i];
            const float cs = gbins[NBINS + i];
            const float as = gbins[2 * NBINS + i];
            if (c > 0.0f) {
                const float gap = fabsf(cs / c - as / c);
                ece += gap * (c * invN);
                mce = fmaxf(mce, gap);
            }
        }
        out[0] = ece;
        out[1] = mce;
    }
}

extern "C" void kernel_launch(void* const* d_in, const int* in_sizes, int n_in,
                              void* d_out, int out_size, void* d_ws, size_t ws_size,
                              hipStream_t stream) {
    const f32x4* logits4     = (const f32x4*)d_in[0];
    const int*   labels      = (const int*)d_in[1];
    const float* temperature = (const float*)d_in[2];
    float*       out         = (float*)d_out;
    float*       gbins       = (float*)d_ws;

    const int N = in_sizes[1];  // number of rows / labels

    hipMemsetAsync(gbins, 0, 3 * NBINS * sizeof(float), stream);

    const int block = 256;
    const int grid  = 2048;
    ece_partial<<<grid, block, 0, stream>>>(logits4, labels, temperature, gbins, N);
    ece_finalize<<<1, 64, 0, stream>>>(gbins, out, 1.0f / (float)N);
}